// Round 16
// baseline (391.874 us; speedup 1.0000x reference)
//
#include <hip/hip_runtime.h>
#include <hip/hip_cooperative_groups.h>
#include <math.h>

namespace cg = cooperative_groups;

#define N_RES 8192
#define N_IN  128
#define BATCH 16
#define LEAK  0.9f

#define NBK    128     // buckets (row>>6), 64 rows each
#define CAP1B  55296   // per-bucket capacity (avg 53248, sigma~230, +8.9 sigma)
#define CHUNK1 8192    // pass1 entries per block-iteration (proven best)
#define CHUNK2 4096    // pass2 entries per unit (proven best)
#define SB2    14      // ceil(CAP1B / CHUNK2) chunks per bucket
#define TBLK   128     // transpose blocks (fallback path only)
#define GRID_B 512     // cooperative grid: 2 blocks/CU x 256 CU

// Entry encoding: y = (row << 14) | col, row 13 bits, col 14 bits (0..8319).
//   bucket = y >> 20 (row>>6); local row rr = (y >> 14) & 63; col = y & 16383.

// ws layout (bytes):
//   srcT @ 0      : [8320][16] f32 transposed state|x   (532,480)
//   bcur @ 1 MiB  : int[128]
//   z    @ 2 MiB  : [N_RES][BATCH] f32                  (524,288)
//   e1   @ 8 MiB  : uint2[NBK][CAP1B]                   (56,623,104)
// Falsified levers (do not retry):
//  R1/R2: FP atomicAdd on LDS -> CAS retry loop, 568us (INT ds_add is native).
//  R5: line-padding bcur -> no change. R6: done-counter finalize fusion ->
//  430us pathology. R8: predicated pipeline -> re-serialized. R10:
//  sched_barrier MLP -> flat. R15: 4-way replicated acc -> conflicts FLAT
//  (7.1M): they are random-bank scatter, not same-address; irreducible.
// R16: kernels sum ~105us but totals ~185us -> ~80us = 5 graph nodes x
//  ~16us. Fuse everything into ONE cooperative persistent kernel.
#define OFF_SRCT 0
#define OFF_BCUR (1u << 20)
#define OFF_Z    (2u << 20)
#define OFF_E1   (8u << 20)
#define REQ_A    ((size_t)OFF_E1 + (size_t)NBK * CAP1B * 8)   // ~62 MiB

// ---------------------------------------------------------------------------
// Fused cooperative kernel: phase0 transpose/zero -> sync -> phase1 binning
// -> sync -> phase2 accumulate -> sync -> phase3 finalize. 512 blocks x
// 1024 threads = exactly 2 blocks/CU (67KB LDS x2 = 134KB < 160KB; VGPR
// capped at 64 by launch_bounds; bodies measured 12-52). All __syncthreads
// are block-uniform; per-block barrier counts may differ across blocks
// (legal). grid.sync() provides device-scope fences for cross-phase
// visibility (G16). Phase bodies are byte-level copies of the proven
// R12 (binning) and R14 (sort-free int-atomic accumulate) kernels.
__global__ __launch_bounds__(1024, 8) void fused_all(
    const float* __restrict__ state,   // [BATCH][N_RES]
    const float* __restrict__ x,       // [BATCH][N_IN]
    const float* __restrict__ vres, const int* __restrict__ rres,
    const int* __restrict__ cres, int nres, int nbres,
    const float* __restrict__ vin, const int* __restrict__ rin,
    const int* __restrict__ cin, int nin, int nchunks,
    float* __restrict__ srcT,          // [8320][16]
    float* __restrict__ z,             // [N_RES][BATCH]
    uint2* __restrict__ e1,            // [NBK][CAP1B]
    int* __restrict__ bcur,            // [NBK]
    const float* __restrict__ res_bias,
    const float* __restrict__ in_bias,
    float* __restrict__ out) {         // [BATCH][N_RES]
  cg::grid_group grid = cg::this_grid();
  int tid = threadIdx.x;
  int bid = blockIdx.x;

  __shared__ __align__(16) char smem[CHUNK1 * 8 + 1536];   // 67072 B

  // ---- Phase 0: transpose srcT, zero z, zero bcur ----
  {
    int idx = bid * 1024 + tid;              // 524288 threads >= all work
    if (idx < N_RES * BATCH) {
      int b = idx >> 13;
      int r = idx & (N_RES - 1);
      srcT[r * BATCH + b] = state[idx];
      z[idx] = 0.0f;
    }
    if (idx < N_IN * BATCH) {
      int b = idx >> 7;
      int c = idx & (N_IN - 1);
      srcT[(N_RES + c) * BATCH + b] = x[idx];
    }
    if (idx < NBK) bcur[idx] = 0;
  }
  grid.sync();

  // ---- Phase 1: binning (grid-stride over chunks; body = R12) ----
  {
    uint2* stg = (uint2*)smem;                       // 64 KB
    int* hist  = (int*)(smem + CHUNK1 * 8);          // 512 B
    int* lbase = (int*)(smem + CHUNK1 * 8 + 512);
    int* gbase = (int*)(smem + CHUNK1 * 8 + 1024);
    int* wsum  = (int*)(smem + CHUNK1 * 8 + 1528);   // 2 ints
    int wave = tid >> 6, lane = tid & 63;

    for (int chk = bid; chk < nchunks; chk += GRID_B) {
      const float* vals; const int* rows; const int* cols;
      int nnz, col_off, base;
      if (chk < nbres) {
        vals = vres; rows = rres; cols = cres; nnz = nres; col_off = 0;
        base = chk * CHUNK1;
      } else {
        vals = vin; rows = rin; cols = cin; nnz = nin; col_off = N_RES;
        base = (chk - nbres) * CHUNK1;
      }

      if (tid < NBK) hist[tid] = 0;
      __syncthreads();

      int n = nnz - base;
      if (n > CHUNK1) n = CHUNK1;

      uint2 ent[8];
      int lp[8];
      unsigned msk = 0;
#pragma unroll
      for (int gg = 0; gg < 2; ++gg) {
        int i0 = (gg * 1024 + tid) * 4;            // 16B-aligned vector offset
        if (i0 + 3 < n) {
          int4 r4 = *(const int4*)(rows + base + i0);
          int4 c4 = *(const int4*)(cols + base + i0);
          float4 v4 = *(const float4*)(vals + base + i0);
          int rr_[4] = {r4.x, r4.y, r4.z, r4.w};
          int cc_[4] = {c4.x, c4.y, c4.z, c4.w};
          float vv_[4] = {v4.x, v4.y, v4.z, v4.w};
#pragma unroll
          for (int j = 0; j < 4; ++j) {
            int e = gg * 4 + j;
            ent[e] = make_uint2(__float_as_uint(vv_[j]),
                                ((unsigned)rr_[j] << 14) |
                                    (unsigned)(cc_[j] + col_off));
            msk |= 1u << e;
            lp[e] = atomicAdd(&hist[rr_[j] >> 6], 1);
          }
        } else {
#pragma unroll
          for (int j = 0; j < 4; ++j) {
            int e = gg * 4 + j, i = i0 + j;
            if (i < n) {
              int r = rows[base + i];
              int c = cols[base + i] + col_off;
              float v = vals[base + i];
              ent[e] = make_uint2(__float_as_uint(v),
                                  ((unsigned)r << 14) | (unsigned)c);
              msk |= 1u << e;
              lp[e] = atomicAdd(&hist[r >> 6], 1);
            }
          }
        }
      }
      __syncthreads();

      int h = 0, v = 0;
      if (tid < NBK) {                           // waves 0,1 scan 128 bins
        h = hist[tid];
        v = h;
#pragma unroll
        for (int d = 1; d < 64; d <<= 1) {
          int t = __shfl_up(v, d);
          if (lane >= d) v += t;
        }
        if (lane == 63) wsum[wave] = v;
      }
      __syncthreads();
      if (tid < NBK) {
        int off = (wave == 1) ? wsum[0] : 0;
        lbase[tid] = off + v - h;
        gbase[tid] = h ? atomicAdd(&bcur[tid], h) : 0;
      }
      __syncthreads();
#pragma unroll
      for (int e = 0; e < 8; ++e) {
        if (msk & (1u << e)) {
          int b = (int)(ent[e].y >> 20);         // recompute bin
          stg[lbase[b] + lp[e]] = ent[e];
        }
      }
      __syncthreads();
      for (int i = tid; i < n; i += 1024) {
        uint2 ld = stg[i];
        int b = (int)(ld.y >> 20);
        int p = gbase[b] + (i - lbase[b]);
        if (p < CAP1B) e1[(size_t)b * CAP1B + p] = ld;
      }
      // next iteration's first __syncthreads orders stg reuse
    }
  }
  grid.sync();

  // ---- Phase 2: sort-free int-atomic accumulate (body = R14) ----
  {
    int* acc = (int*)smem;                // 64*17 ints = 4352 B
    int wave = tid >> 6, lane = tid & 63;
    int g = lane >> 2;                    // entry slot within 16-entry step
    int bq = lane & 3;                    // batch quad
    const float4* __restrict__ s4 = (const float4*)srcT;

    for (int u = bid; u < SB2 * NBK; u += GRID_B) {
      int bucket = u & (NBK - 1);
      int ch = u >> 7;                    // 0..SB2-1
      int cnt = bcur[bucket];
      if (cnt > CAP1B) cnt = CAP1B;
      int base = ch * CHUNK2;
      int n = cnt - base;
      if (n < 0) n = 0;
      if (n > CHUNK2) n = CHUNK2;

      for (int i = tid; i < 64 * 17; i += 1024) acc[i] = 0;
      __syncthreads();

      if (n > 0) {
        const uint2* __restrict__ src = e1 + (size_t)bucket * CAP1B + base;
        // 16 waves, each owns a 256-entry span; 2 entries/slot/iter.
        int bw = wave * (CHUNK2 / 16);
        int lim = n - bw;
        if (lim < 0) lim = 0;
        if (lim > CHUNK2 / 16) lim = CHUNK2 / 16;
        for (int s = 0; s < lim; s += 32) {
          int i1 = bw + s + g;
          int i2 = bw + s + 16 + g;
          int c1 = (i1 < n) ? i1 : n - 1;
          int c2 = (i2 < n) ? i2 : n - 1;
          uint2 eA = src[c1];
          uint2 eB = src[c2];
          float4 sA = s4[(int)(eA.y & 16383u) * 4 + bq];
          float4 sB = s4[(int)(eB.y & 16383u) * 4 + bq];
          float vA = (i1 < n) ? __uint_as_float(eA.x) * 65536.f : 0.0f;
          float vB = (i2 < n) ? __uint_as_float(eB.x) * 65536.f : 0.0f;
          int aA = (int)((eA.y >> 14) & 63u) * 17 + (bq << 2);
          int aB = (int)((eB.y >> 14) & 63u) * 17 + (bq << 2);
          atomicAdd(&acc[aA + 0], __float2int_rn(vA * sA.x));
          atomicAdd(&acc[aA + 1], __float2int_rn(vA * sA.y));
          atomicAdd(&acc[aA + 2], __float2int_rn(vA * sA.z));
          atomicAdd(&acc[aA + 3], __float2int_rn(vA * sA.w));
          atomicAdd(&acc[aB + 0], __float2int_rn(vB * sB.x));
          atomicAdd(&acc[aB + 1], __float2int_rn(vB * sB.y));
          atomicAdd(&acc[aB + 2], __float2int_rn(vB * sB.z));
          atomicAdd(&acc[aB + 3], __float2int_rn(vB * sB.w));
        }
      }
      __syncthreads();
      if (n > 0 && tid < 64 * BATCH) {    // 1024 threads cover 64x16
        int rr = tid >> 4, b = tid & 15;
        float fv = (float)acc[rr * 17 + b] * (1.0f / 65536.f);
        unsafeAtomicAdd(&z[(size_t)(bucket * 64 + rr) * BATCH + b], fv);
      }
      __syncthreads();                    // protect acc reuse next unit
    }
  }
  grid.sync();

  // ---- Phase 3: finalize ----
  {
    int idx = bid * 1024 + tid;
    if (idx < BATCH * N_RES) {
      int b = idx >> 13;
      int r = idx & (N_RES - 1);
      float zz = z[r * 16 + b] + res_bias[r] + in_bias[r];
      out[idx] = (1.0f - LEAK) * state[idx] + LEAK * erff(zz);
    }
  }
}

// ---------------------------------------------------------------------------
// Fallback path (non-cooperative): EXACT R14 kernels (proven 185.9us total).
__global__ __launch_bounds__(1024, 8) void pass1_fused(
    const float* __restrict__ state, const float* __restrict__ x,
    const float* __restrict__ vres, const int* __restrict__ rres,
    const int* __restrict__ cres, int nres, int nbres,
    const float* __restrict__ vin, const int* __restrict__ rin,
    const int* __restrict__ cin, int nin, int nchunks,
    float* __restrict__ srcT, float* __restrict__ z,
    uint2* __restrict__ e1, int* __restrict__ bcur) {
  int tid = threadIdx.x;

  if (blockIdx.x >= nchunks) {
    int idx0 = (blockIdx.x - nchunks) * 1024 + tid;
    const int stride = TBLK * 1024;
    for (int i = idx0; i < N_RES * BATCH; i += stride) {
      int b = i >> 13;
      int r = i & (N_RES - 1);
      srcT[r * BATCH + b] = state[i];
      z[i] = 0.0f;
    }
    for (int i = idx0; i < N_IN * BATCH; i += stride) {
      int b = i >> 7;
      int c = i & (N_IN - 1);
      srcT[(N_RES + c) * BATCH + b] = x[i];
    }
    return;
  }

  const float* vals; const int* rows; const int* cols;
  int nnz, col_off, base;
  if (blockIdx.x < nbres) {
    vals = vres; rows = rres; cols = cres; nnz = nres; col_off = 0;
    base = blockIdx.x * CHUNK1;
  } else {
    vals = vin; rows = rin; cols = cin; nnz = nin; col_off = N_RES;
    base = (blockIdx.x - nbres) * CHUNK1;
  }

  __shared__ uint2 stg[CHUNK1];
  __shared__ int hist[NBK];
  __shared__ int lbase[NBK];
  __shared__ int gbase[NBK];
  __shared__ int wsum[2];
  int wave = tid >> 6, lane = tid & 63;

  if (tid < NBK) hist[tid] = 0;
  __syncthreads();

  int n = nnz - base;
  if (n > CHUNK1) n = CHUNK1;

  uint2 ent[8];
  int lp[8];
  unsigned msk = 0;
#pragma unroll
  for (int g = 0; g < 2; ++g) {
    int i0 = (g * 1024 + tid) * 4;
    if (i0 + 3 < n) {
      int4 r4 = *(const int4*)(rows + base + i0);
      int4 c4 = *(const int4*)(cols + base + i0);
      float4 v4 = *(const float4*)(vals + base + i0);
      int rr_[4] = {r4.x, r4.y, r4.z, r4.w};
      int cc_[4] = {c4.x, c4.y, c4.z, c4.w};
      float vv_[4] = {v4.x, v4.y, v4.z, v4.w};
#pragma unroll
      for (int j = 0; j < 4; ++j) {
        int e = g * 4 + j;
        ent[e] = make_uint2(__float_as_uint(vv_[j]),
                            ((unsigned)rr_[j] << 14) |
                                (unsigned)(cc_[j] + col_off));
        msk |= 1u << e;
        lp[e] = atomicAdd(&hist[rr_[j] >> 6], 1);
      }
    } else {
#pragma unroll
      for (int j = 0; j < 4; ++j) {
        int e = g * 4 + j, i = i0 + j;
        if (i < n) {
          int r = rows[base + i];
          int c = cols[base + i] + col_off;
          float v = vals[base + i];
          ent[e] = make_uint2(__float_as_uint(v),
                              ((unsigned)r << 14) | (unsigned)c);
          msk |= 1u << e;
          lp[e] = atomicAdd(&hist[r >> 6], 1);
        }
      }
    }
  }
  __syncthreads();

  int h = 0, v = 0;
  if (tid < NBK) {
    h = hist[tid];
    v = h;
#pragma unroll
    for (int d = 1; d < 64; d <<= 1) {
      int t = __shfl_up(v, d);
      if (lane >= d) v += t;
    }
    if (lane == 63) wsum[wave] = v;
  }
  __syncthreads();
  if (tid < NBK) {
    int off = (wave == 1) ? wsum[0] : 0;
    lbase[tid] = off + v - h;
    gbase[tid] = h ? atomicAdd(&bcur[tid], h) : 0;
  }
  __syncthreads();
#pragma unroll
  for (int e = 0; e < 8; ++e) {
    if (msk & (1u << e)) {
      int b = (int)(ent[e].y >> 20);
      stg[lbase[b] + lp[e]] = ent[e];
    }
  }
  __syncthreads();
  for (int i = tid; i < n; i += 1024) {
    uint2 ld = stg[i];
    int b = (int)(ld.y >> 20);
    int p = gbase[b] + (i - lbase[b]);
    if (p < CAP1B) e1[(size_t)b * CAP1B + p] = ld;
  }
}

__global__ __launch_bounds__(512, 8) void pass2_accum(
    const uint2* __restrict__ e1, const int* __restrict__ bcur,
    const float* __restrict__ srcT, float* __restrict__ z) {
  int bucket = blockIdx.y;
  int ch = blockIdx.x;
  int tid = threadIdx.x;

  int cnt = bcur[bucket];
  if (cnt > CAP1B) cnt = CAP1B;
  int base = ch * CHUNK2;
  if (base >= cnt) return;
  int n = cnt - base;
  if (n > CHUNK2) n = CHUNK2;

  __shared__ int acc[64 * 17];
  for (int i = tid; i < 64 * 17; i += 512) acc[i] = 0;
  __syncthreads();

  const uint2* __restrict__ src = e1 + (size_t)bucket * CAP1B + base;
  int wave = tid >> 6, lane = tid & 63;
  int g = lane >> 2;
  int bq = lane & 3;
  const float4* __restrict__ s4 = (const float4*)srcT;

  int bw = wave * (CHUNK2 / 8);
  int lim = n - bw;
  if (lim > CHUNK2 / 8) lim = CHUNK2 / 8;
  for (int s = 0; s < lim; s += 32) {
    int i1 = bw + s + g;
    int i2 = bw + s + 16 + g;
    int c1 = (i1 < n) ? i1 : n - 1;
    int c2 = (i2 < n) ? i2 : n - 1;
    uint2 eA = src[c1];
    uint2 eB = src[c2];
    float4 sA = s4[(int)(eA.y & 16383u) * 4 + bq];
    float4 sB = s4[(int)(eB.y & 16383u) * 4 + bq];
    float vA = (i1 < n) ? __uint_as_float(eA.x) * 65536.f : 0.0f;
    float vB = (i2 < n) ? __uint_as_float(eB.x) * 65536.f : 0.0f;
    int aA = (int)((eA.y >> 14) & 63u) * 17 + (bq << 2);
    int aB = (int)((eB.y >> 14) & 63u) * 17 + (bq << 2);
    atomicAdd(&acc[aA + 0], __float2int_rn(vA * sA.x));
    atomicAdd(&acc[aA + 1], __float2int_rn(vA * sA.y));
    atomicAdd(&acc[aA + 2], __float2int_rn(vA * sA.z));
    atomicAdd(&acc[aA + 3], __float2int_rn(vA * sA.w));
    atomicAdd(&acc[aB + 0], __float2int_rn(vB * sB.x));
    atomicAdd(&acc[aB + 1], __float2int_rn(vB * sB.y));
    atomicAdd(&acc[aB + 2], __float2int_rn(vB * sB.z));
    atomicAdd(&acc[aB + 3], __float2int_rn(vB * sB.w));
  }
  __syncthreads();
  for (int i = tid; i < 64 * BATCH; i += 512) {
    int rr = i >> 4, b = i & 15;
    float fv = (float)acc[rr * 17 + b] * (1.0f / 65536.f);
    unsafeAtomicAdd(&z[(size_t)(bucket * 64 + rr) * BATCH + b], fv);
  }
}

__global__ __launch_bounds__(256) void finalize_z(
    const float* __restrict__ z, const float* __restrict__ state,
    const float* __restrict__ res_bias, const float* __restrict__ in_bias,
    float* __restrict__ out) {
  int tid = blockIdx.x * 256 + threadIdx.x;
  if (tid >= BATCH * N_RES) return;
  int b = tid >> 13;
  int r = tid & (N_RES - 1);
  float zz = z[r * 16 + b] + res_bias[r] + in_bias[r];
  out[tid] = (1.0f - LEAK) * state[tid] + LEAK * erff(zz);
}

// ---------------------------------------------------------------------------
// Small-ws fallback: atomic path, correct but slow.
__global__ __launch_bounds__(256) void transpose_nb(
    const float* __restrict__ state, const float* __restrict__ x,
    float* __restrict__ srcT) {
  int tid = blockIdx.x * 256 + threadIdx.x;
  if (tid < N_RES * BATCH) {
    int b = tid >> 13;
    int r = tid & (N_RES - 1);
    srcT[r * BATCH + b] = state[tid];
  }
  if (tid < N_IN * BATCH) {
    int b = tid >> 7;
    int c = tid & (N_IN - 1);
    srcT[(N_RES + c) * BATCH + b] = x[tid];
  }
}

__global__ __launch_bounds__(256) void spmm_atomic(
    const float* __restrict__ vals, const int* __restrict__ rows,
    const int* __restrict__ cols, const float* __restrict__ srcT,
    int col_off, float* __restrict__ zz, int nnz) {
  int i = blockIdx.x * blockDim.x + threadIdx.x;
  if (i >= nnz) return;
  float v = vals[i];
  int r = rows[i];
  int c = cols[i] + col_off;
  const float4* __restrict__ sp = (const float4*)(srcT + c * BATCH);
  float* zr = zz + r * BATCH;
#pragma unroll
  for (int qq = 0; qq < 4; ++qq) {
    float4 s = sp[qq];
    unsafeAtomicAdd(zr + qq * 4 + 0, v * s.x);
    unsafeAtomicAdd(zr + qq * 4 + 1, v * s.y);
    unsafeAtomicAdd(zr + qq * 4 + 2, v * s.z);
    unsafeAtomicAdd(zr + qq * 4 + 3, v * s.w);
  }
}

// ---------------------------------------------------------------------------
extern "C" void kernel_launch(void* const* d_in, const int* in_sizes, int n_in,
                              void* d_out, int out_size, void* d_ws, size_t ws_size,
                              hipStream_t stream) {
  const float* state    = (const float*)d_in[0];
  const float* x        = (const float*)d_in[1];
  const float* res_vals = (const float*)d_in[2];
  const int*   res_rows = (const int*)d_in[3];
  const int*   res_cols = (const int*)d_in[4];
  const float* res_bias = (const float*)d_in[5];
  const float* in_vals  = (const float*)d_in[6];
  const int*   in_rows  = (const int*)d_in[7];
  const int*   in_cols  = (const int*)d_in[8];
  const float* in_bias  = (const float*)d_in[9];

  const int res_nnz = in_sizes[2];
  const int in_nnz  = in_sizes[6];

  char* ws = (char*)d_ws;
  float* srcT = (float*)(ws + OFF_SRCT);
  float* z    = (float*)(ws + OFF_Z);
  float* out  = (float*)d_out;

  if (ws_size >= REQ_A) {
    int* bcur = (int*)(ws + OFF_BCUR);
    uint2* e1 = (uint2*)(ws + OFF_E1);
    int nbres = (res_nnz + CHUNK1 - 1) / CHUNK1;
    int nbin  = (in_nnz + CHUNK1 - 1) / CHUNK1;
    int nchunks = nbres + nbin;

    // Try the single cooperative dispatch first (eliminates ~4 graph-node
    // overheads, ~16us each). Fall back to the proven 3-kernel path on any
    // failure (unsupported device / capture restriction).
    int coop = 0;
    hipDeviceGetAttribute(&coop, hipDeviceAttributeCooperativeLaunch, 0);
    hipError_t lerr = hipErrorUnknown;
    if (coop) {
      void* args[] = {
          (void*)&state, (void*)&x,
          (void*)&res_vals, (void*)&res_rows, (void*)&res_cols,
          (void*)&res_nnz, (void*)&nbres,
          (void*)&in_vals, (void*)&in_rows, (void*)&in_cols,
          (void*)&in_nnz, (void*)&nchunks,
          (void*)&srcT, (void*)&z, (void*)&e1, (void*)&bcur,
          (void*)&res_bias, (void*)&in_bias, (void*)&out};
      lerr = hipLaunchCooperativeKernel((const void*)fused_all,
                                        dim3(GRID_B), dim3(1024),
                                        args, 0, stream);
    }
    if (lerr != hipSuccess) {
      (void)hipGetLastError();          // clear error state
      hipMemsetAsync(bcur, 0, NBK * sizeof(int), stream);
      pass1_fused<<<nchunks + TBLK, 1024, 0, stream>>>(
          state, x, res_vals, res_rows, res_cols, res_nnz, nbres,
          in_vals, in_rows, in_cols, in_nnz, nchunks, srcT, z, e1, bcur);
      pass2_accum<<<dim3(SB2, NBK), 512, 0, stream>>>(e1, bcur, srcT, z);
      finalize_z<<<512, 256, 0, stream>>>(z, state, res_bias, in_bias, out);
    }
  } else {
    hipMemsetAsync(z, 0, N_RES * BATCH * sizeof(float), stream);
    transpose_nb<<<512, 256, 0, stream>>>(state, x, srcT);
    spmm_atomic<<<(res_nnz + 255) / 256, 256, 0, stream>>>(
        res_vals, res_rows, res_cols, srcT, 0, z, res_nnz);
    spmm_atomic<<<(in_nnz + 255) / 256, 256, 0, stream>>>(
        in_vals, in_rows, in_cols, srcT, N_RES, z, in_nnz);
    finalize_z<<<512, 256, 0, stream>>>(z, state, res_bias, in_bias, out);
  }
}

// Round 17
// 185.670 us; speedup vs baseline: 2.1106x; 2.1106x over previous
//
#include <hip/hip_runtime.h>
#include <math.h>

#define N_RES 8192
#define N_IN  128
#define BATCH 16
#define LEAK  0.9f

#define NBK    128     // buckets (row>>6), 64 rows each
#define CAP1B  55296   // per-bucket capacity (avg 53248, sigma~230, +8.9 sigma)
#define CHUNK1 8192    // pass1 entries per block (2048->77us, 4096->60us, 8192 best)
#define CHUNK2 4096    // pass2 entries per block (1792 blocks fills wave slots)
#define SB2    14      // ceil(CAP1B / CHUNK2) chunks per bucket
#define TBLK   128     // transpose blocks appended to pass1 grid

// Entry encoding: y = (row << 14) | col, row 13 bits, col 14 bits (0..8319).
//   bucket = y >> 20 (row>>6); local row rr = (y >> 14) & 63; col = y & 16383.

// ws layout (bytes):
//   srcT @ 0      : [8320][16] f32 transposed state|x, PRE-SCALED by 2^16
//   bcur @ 1 MiB  : int[128]
//   z    @ 2 MiB  : [N_RES][BATCH] f32                  (524,288)
//   e1   @ 8 MiB  : uint2[NBK][CAP1B]                   (56,623,104)
// Falsified levers (do not retry):
//  R1/R2: FP atomicAdd on LDS -> CAS retry loop, 568us (INT ds_add native).
//  R5: line-padding bcur -> no change. R6: done-counter finalize fusion ->
//  430us pathology. R8: predicated pipeline -> re-serialized. R10:
//  sched_barrier MLP -> flat. R15: 4-way replicated acc -> conflicts flat
//  (random-bank scatter, irreducible). R16: cooperative single-kernel
//  fusion -> kernel itself 270us (vs 105 sum), 0.5 TB/s effective:
//  grid.sync cross-XCD coherence kills L2 locality on 8-XCD gfx950.
#define OFF_SRCT 0
#define OFF_BCUR (1u << 20)
#define OFF_Z    (2u << 20)
#define OFF_E1   (8u << 20)
#define REQ_A    ((size_t)OFF_E1 + (size_t)NBK * CAP1B * 8)   // ~62 MiB

// ---------------------------------------------------------------------------
// K1: EXACT R12/R14 version (45.9us) except srcT is stored PRE-SCALED by
// 2^16 (srcT is consumed only by pass2's fixed-point accumulate; saves one
// v_mul per entry there). pass1 binning (blocks [0, nchunks)) + transpose/
// z-zero (blocks [nchunks, +TBLK)). bcur pre-zeroed. 1024 threads @
// CHUNK1=8192 (64KB stg): 2 blocks/CU x 16 waves = 32 waves/CU.
__global__ __launch_bounds__(1024, 8) void pass1_fused(
    const float* __restrict__ state,   // [BATCH][N_RES]
    const float* __restrict__ x,       // [BATCH][N_IN]
    const float* __restrict__ vres, const int* __restrict__ rres,
    const int* __restrict__ cres, int nres, int nbres,
    const float* __restrict__ vin, const int* __restrict__ rin,
    const int* __restrict__ cin, int nin, int nchunks,
    float* __restrict__ srcT,          // [8320][16], pre-scaled 2^16
    float* __restrict__ z,             // [N_RES][BATCH] (zeroed here)
    uint2* __restrict__ e1,            // [NBK][CAP1B]
    int* __restrict__ bcur) {          // [NBK] (pre-zeroed)
  int tid = threadIdx.x;

  if (blockIdx.x >= nchunks) {         // ---- transpose + z-zero section ----
    int idx0 = (blockIdx.x - nchunks) * 1024 + tid;
    const int stride = TBLK * 1024;
    for (int i = idx0; i < N_RES * BATCH; i += stride) {
      int b = i >> 13;
      int r = i & (N_RES - 1);
      srcT[r * BATCH + b] = state[i] * 65536.0f;
      z[i] = 0.0f;
    }
    for (int i = idx0; i < N_IN * BATCH; i += stride) {
      int b = i >> 7;
      int c = i & (N_IN - 1);
      srcT[(N_RES + c) * BATCH + b] = x[i] * 65536.0f;
    }
    return;                            // block-uniform; no barriers used here
  }

  // ---- binning section ----
  const float* vals; const int* rows; const int* cols;
  int nnz, col_off, base;
  if (blockIdx.x < nbres) {
    vals = vres; rows = rres; cols = cres; nnz = nres; col_off = 0;
    base = blockIdx.x * CHUNK1;
  } else {
    vals = vin; rows = rin; cols = cin; nnz = nin; col_off = N_RES;
    base = (blockIdx.x - nbres) * CHUNK1;
  }

  __shared__ uint2 stg[CHUNK1];              // 64 KB
  __shared__ int hist[NBK];
  __shared__ int lbase[NBK];
  __shared__ int gbase[NBK];
  __shared__ int wsum[2];
  int wave = tid >> 6, lane = tid & 63;

  if (tid < NBK) hist[tid] = 0;
  __syncthreads();

  int n = nnz - base;
  if (n > CHUNK1) n = CHUNK1;

  uint2 ent[8];
  int lp[8];
  unsigned msk = 0;
#pragma unroll
  for (int g = 0; g < 2; ++g) {
    int i0 = (g * 1024 + tid) * 4;           // 16B-aligned vector offset
    if (i0 + 3 < n) {
      int4 r4 = *(const int4*)(rows + base + i0);
      int4 c4 = *(const int4*)(cols + base + i0);
      float4 v4 = *(const float4*)(vals + base + i0);
      int rr_[4] = {r4.x, r4.y, r4.z, r4.w};
      int cc_[4] = {c4.x, c4.y, c4.z, c4.w};
      float vv_[4] = {v4.x, v4.y, v4.z, v4.w};
#pragma unroll
      for (int j = 0; j < 4; ++j) {
        int e = g * 4 + j;
        ent[e] = make_uint2(__float_as_uint(vv_[j]),
                            ((unsigned)rr_[j] << 14) |
                                (unsigned)(cc_[j] + col_off));
        msk |= 1u << e;
        lp[e] = atomicAdd(&hist[rr_[j] >> 6], 1);
      }
    } else {
#pragma unroll
      for (int j = 0; j < 4; ++j) {
        int e = g * 4 + j, i = i0 + j;
        if (i < n) {
          int r = rows[base + i];
          int c = cols[base + i] + col_off;
          float v = vals[base + i];
          ent[e] = make_uint2(__float_as_uint(v),
                              ((unsigned)r << 14) | (unsigned)c);
          msk |= 1u << e;
          lp[e] = atomicAdd(&hist[r >> 6], 1);
        }
      }
    }
  }
  __syncthreads();

  int h = 0, v = 0;
  if (tid < NBK) {                           // waves 0,1 scan 128 bins
    h = hist[tid];
    v = h;
#pragma unroll
    for (int d = 1; d < 64; d <<= 1) {
      int t = __shfl_up(v, d);
      if (lane >= d) v += t;
    }
    if (lane == 63) wsum[wave] = v;
  }
  __syncthreads();
  if (tid < NBK) {
    int off = (wave == 1) ? wsum[0] : 0;
    lbase[tid] = off + v - h;
    gbase[tid] = h ? atomicAdd(&bcur[tid], h) : 0;
  }
  __syncthreads();
#pragma unroll
  for (int e = 0; e < 8; ++e) {
    if (msk & (1u << e)) {
      int b = (int)(ent[e].y >> 20);         // recompute bin from packed row
      stg[lbase[b] + lp[e]] = ent[e];
    }
  }
  __syncthreads();
  for (int i = tid; i < n; i += 1024) {
    uint2 ld = stg[i];
    int b = (int)(ld.y >> 20);
    int p = gbase[b] + (i - lbase[b]);
    if (p < CAP1B) e1[(size_t)b * CAP1B + p] = ld;
  }
}

// ---------------------------------------------------------------------------
// K2 (R17): sort-free fixed-point accumulation, branch-free main loop.
// R14 PMC: VALUBusy 37% ~= 17us of pass2's 45us; the per-iteration clamp/
// mask predication is dead weight for the ~94% of iterations that are full.
// Main loop over lim&~31 entries is UNGUARDED (no cmp/cndmask); one guarded
// tail step handles the remainder. srcT arrives pre-scaled by 2^16 (pass1)
// -> no per-entry scaling mul. acc[64][17] INT accumulator (4.4KB LDS) +
// native ds_add. 512 threads, 1792 blocks = full 32 waves/CU (R14).
// Readback: 1024 global unsafeAtomicAdd into z. Grid: (SB2, NBK).
__global__ __launch_bounds__(512, 8) void pass2_accum(
    const uint2* __restrict__ e1,
    const int* __restrict__ bcur,
    const float* __restrict__ srcT,     // [8320][16], pre-scaled 2^16
    float* __restrict__ z) {            // [N_RES][BATCH] (pre-zeroed)
  int bucket = blockIdx.y;
  int ch = blockIdx.x;
  int tid = threadIdx.x;

  int cnt = bcur[bucket];
  if (cnt > CAP1B) cnt = CAP1B;
  int base = ch * CHUNK2;
  if (base >= cnt) return;              // block-uniform early exit
  int n = cnt - base;
  if (n > CHUNK2) n = CHUNK2;

  __shared__ int acc[64 * 17];          // 4352 B, fixed-point 2^-16
  for (int i = tid; i < 64 * 17; i += 512) acc[i] = 0;
  __syncthreads();

  const uint2* __restrict__ src = e1 + (size_t)bucket * CAP1B + base;
  int wave = tid >> 6, lane = tid & 63;
  int g = lane >> 2;                    // entry slot within 16-entry step
  int bq = lane & 3;                    // batch quad
  const float4* __restrict__ s4 = (const float4*)srcT;

  // Each wave owns a contiguous 512-entry span.
  int bw = wave * (CHUNK2 / 8);
  int lim = n - bw;
  if (lim < 0) lim = 0;
  if (lim > CHUNK2 / 8) lim = CHUNK2 / 8;
  int full = lim & ~31;                 // unguarded portion (mult. of 32)

  for (int s = 0; s < full; s += 32) {  // branch-free: no clamps, no masks
    int i1 = bw + s + g;
    int i2 = bw + s + 16 + g;
    uint2 eA = src[i1];
    uint2 eB = src[i2];
    float4 sA = s4[(int)(eA.y & 16383u) * 4 + bq];
    float4 sB = s4[(int)(eB.y & 16383u) * 4 + bq];
    float vA = __uint_as_float(eA.x);
    float vB = __uint_as_float(eB.x);
    int aA = (int)((eA.y >> 14) & 63u) * 17 + (bq << 2);
    int aB = (int)((eB.y >> 14) & 63u) * 17 + (bq << 2);
    atomicAdd(&acc[aA + 0], __float2int_rn(vA * sA.x));
    atomicAdd(&acc[aA + 1], __float2int_rn(vA * sA.y));
    atomicAdd(&acc[aA + 2], __float2int_rn(vA * sA.z));
    atomicAdd(&acc[aA + 3], __float2int_rn(vA * sA.w));
    atomicAdd(&acc[aB + 0], __float2int_rn(vB * sB.x));
    atomicAdd(&acc[aB + 1], __float2int_rn(vB * sB.y));
    atomicAdd(&acc[aB + 2], __float2int_rn(vB * sB.z));
    atomicAdd(&acc[aB + 3], __float2int_rn(vB * sB.w));
  }
  if (full < lim) {                     // guarded tail (<32 entries)
    int i1 = bw + full + g;
    int i2 = bw + full + 16 + g;
    int c1 = (i1 < n && full + g < lim) ? i1 : n - 1;
    int c2 = (i2 < n && full + 16 + g < lim) ? i2 : n - 1;
    uint2 eA = src[c1];
    uint2 eB = src[c2];
    float4 sA = s4[(int)(eA.y & 16383u) * 4 + bq];
    float4 sB = s4[(int)(eB.y & 16383u) * 4 + bq];
    float vA = (full + g < lim) ? __uint_as_float(eA.x) : 0.0f;
    float vB = (full + 16 + g < lim) ? __uint_as_float(eB.x) : 0.0f;
    int aA = (int)((eA.y >> 14) & 63u) * 17 + (bq << 2);
    int aB = (int)((eB.y >> 14) & 63u) * 17 + (bq << 2);
    atomicAdd(&acc[aA + 0], __float2int_rn(vA * sA.x));
    atomicAdd(&acc[aA + 1], __float2int_rn(vA * sA.y));
    atomicAdd(&acc[aA + 2], __float2int_rn(vA * sA.z));
    atomicAdd(&acc[aA + 3], __float2int_rn(vA * sA.w));
    atomicAdd(&acc[aB + 0], __float2int_rn(vB * sB.x));
    atomicAdd(&acc[aB + 1], __float2int_rn(vB * sB.y));
    atomicAdd(&acc[aB + 2], __float2int_rn(vB * sB.z));
    atomicAdd(&acc[aB + 3], __float2int_rn(vB * sB.w));
  }
  __syncthreads();
  // Readback: convert and add into z (multiple chunks per bucket -> atomic).
  for (int i = tid; i < 64 * BATCH; i += 512) {
    int rr = i >> 4, b = i & 15;
    float fv = (float)acc[rr * 17 + b] * (1.0f / 65536.f);
    unsafeAtomicAdd(&z[(size_t)(bucket * 64 + rr) * BATCH + b], fv);
  }
}

// ---------------------------------------------------------------------------
__global__ __launch_bounds__(256) void finalize_z(
    const float* __restrict__ z, const float* __restrict__ state,
    const float* __restrict__ res_bias, const float* __restrict__ in_bias,
    float* __restrict__ out) {
  int tid = blockIdx.x * 256 + threadIdx.x;
  if (tid >= BATCH * N_RES) return;
  int b = tid >> 13;
  int r = tid & (N_RES - 1);
  float zz = z[r * 16 + b] + res_bias[r] + in_bias[r];
  out[tid] = (1.0f - LEAK) * state[tid] + LEAK * erff(zz);
}

// ---------------------------------------------------------------------------
// Fallback (small ws): atomic path, correct but slow. srcT here UNscaled.
__global__ __launch_bounds__(256) void transpose_nb(
    const float* __restrict__ state, const float* __restrict__ x,
    float* __restrict__ srcT) {
  int tid = blockIdx.x * 256 + threadIdx.x;
  if (tid < N_RES * BATCH) {
    int b = tid >> 13;
    int r = tid & (N_RES - 1);
    srcT[r * BATCH + b] = state[tid];
  }
  if (tid < N_IN * BATCH) {
    int b = tid >> 7;
    int c = tid & (N_IN - 1);
    srcT[(N_RES + c) * BATCH + b] = x[tid];
  }
}

__global__ __launch_bounds__(256) void spmm_atomic(
    const float* __restrict__ vals, const int* __restrict__ rows,
    const int* __restrict__ cols, const float* __restrict__ srcT,
    int col_off, float* __restrict__ zz, int nnz) {
  int i = blockIdx.x * blockDim.x + threadIdx.x;
  if (i >= nnz) return;
  float v = vals[i];
  int r = rows[i];
  int c = cols[i] + col_off;
  const float4* __restrict__ sp = (const float4*)(srcT + c * BATCH);
  float* zr = zz + r * BATCH;
#pragma unroll
  for (int qq = 0; qq < 4; ++qq) {
    float4 s = sp[qq];
    unsafeAtomicAdd(zr + qq * 4 + 0, v * s.x);
    unsafeAtomicAdd(zr + qq * 4 + 1, v * s.y);
    unsafeAtomicAdd(zr + qq * 4 + 2, v * s.z);
    unsafeAtomicAdd(zr + qq * 4 + 3, v * s.w);
  }
}

// ---------------------------------------------------------------------------
extern "C" void kernel_launch(void* const* d_in, const int* in_sizes, int n_in,
                              void* d_out, int out_size, void* d_ws, size_t ws_size,
                              hipStream_t stream) {
  const float* state    = (const float*)d_in[0];
  const float* x        = (const float*)d_in[1];
  const float* res_vals = (const float*)d_in[2];
  const int*   res_rows = (const int*)d_in[3];
  const int*   res_cols = (const int*)d_in[4];
  const float* res_bias = (const float*)d_in[5];
  const float* in_vals  = (const float*)d_in[6];
  const int*   in_rows  = (const int*)d_in[7];
  const int*   in_cols  = (const int*)d_in[8];
  const float* in_bias  = (const float*)d_in[9];

  const int res_nnz = in_sizes[2];
  const int in_nnz  = in_sizes[6];

  char* ws = (char*)d_ws;
  float* srcT = (float*)(ws + OFF_SRCT);
  float* z    = (float*)(ws + OFF_Z);
  float* out = (float*)d_out;

  if (ws_size >= REQ_A) {
    int* bcur = (int*)(ws + OFF_BCUR);
    uint2* e1 = (uint2*)(ws + OFF_E1);
    int nbres = (res_nnz + CHUNK1 - 1) / CHUNK1;
    int nbin  = (in_nnz + CHUNK1 - 1) / CHUNK1;
    int nchunks = nbres + nbin;

    hipMemsetAsync(bcur, 0, NBK * sizeof(int), stream);

    pass1_fused<<<nchunks + TBLK, 1024, 0, stream>>>(
        state, x, res_vals, res_rows, res_cols, res_nnz, nbres,
        in_vals, in_rows, in_cols, in_nnz, nchunks, srcT, z, e1, bcur);

    pass2_accum<<<dim3(SB2, NBK), 512, 0, stream>>>(e1, bcur, srcT, z);

    finalize_z<<<512, 256, 0, stream>>>(z, state, res_bias, in_bias, out);
  } else {
    hipMemsetAsync(z, 0, N_RES * BATCH * sizeof(float), stream);
    transpose_nb<<<512, 256, 0, stream>>>(state, x, srcT);
    spmm_atomic<<<(res_nnz + 255) / 256, 256, 0, stream>>>(
        res_vals, res_rows, res_cols, srcT, 0, z, res_nnz);
    spmm_atomic<<<(in_nnz + 255) / 256, 256, 0, stream>>>(
        in_vals, in_rows, in_cols, srcT, N_RES, z, in_nnz);
    finalize_z<<<512, 256, 0, stream>>>(z, state, res_bias, in_bias, out);
  }
}